// Round 5
// baseline (83.188 us; speedup 1.0000x reference)
//
#include <hip/hip_runtime.h>

// PureAEVComputer radial AEV on MI355X — R5: R4 math (2-anchor exp chain,
// 6 trans/pair) + latency-hiding restructure:
//   * 2 waves per atom (each sweeps half the 512 neighbors, 4 unrolled chunks)
//   * 4096 blocks x 256 thr (2 atoms + 2 j-halves per block) => 16384 waves
//   * __launch_bounds__(256,4): cap VGPR at 128 => 4 waves/SIMD resident
//   * per-wave shuffle reduce-scatter, then LDS pair-combine + store

typedef float f2 __attribute__((ext_vector_type(2)));

constexpr int B = 16;
constexpr int N = 512;
constexpr int TARGET = 1008;

__device__ constexpr float SHF(int r) { return 0.9f + 0.26875f * r; }
constexpr float L16 = 23.083120654223414f;   // 16 * log2(e)
constexpr float DEL = 0.26875f;
constexpr float LD  = 6.203588675822543f;    // L16 * DEL
constexpr float LD2 = 12.407177351645086f;   // 2 * L16 * DEL

__global__ __launch_bounds__(256, 4) void aev_radial_kernel(
    const int* __restrict__ species,       // (B, N)
    const float* __restrict__ coordinates, // (B, N, 3)
    float* __restrict__ out)               // (B, N, 1008)
{
    __shared__ float4 sc[N];          // xyz + species bits in .w
    __shared__ float  pairbuf[2][64]; // [atom-in-block][feature]

    const int tid  = threadIdx.x;
    const int bb   = blockIdx.x >> 8;    // batch (256 blocks per batch)
    const int tile = blockIdx.x & 255;   // 2-atom tile

    const float* cb = coordinates + (size_t)bb * (N * 3);
    const int*   sb = species + bb * N;
    for (int a = tid; a < N; a += 256) {
        sc[a] = make_float4(cb[3 * a], cb[3 * a + 1], cb[3 * a + 2],
                            __int_as_float(sb[a]));
    }
    __syncthreads();

    const int wave  = tid >> 6;
    const int lane  = tid & 63;
    const int aib   = wave >> 1;         // atom-in-block: 0..1
    const int jhalf = wave & 1;          // which half of the j range
    const int i     = tile * 2 + aib;

    const float4 ci = sc[i];

    f2 acc[32];
    #pragma unroll
    for (int k = 0; k < 32; ++k) acc[k] = f2{0.0f, 0.0f};

    // chain literals (constant-folded)
    const float Q  = __builtin_exp2f(-2.0f * L16 * DEL * DEL);
    const float KA = __builtin_exp2f(-LD * (SHF(3) + SHF(4)));
    const float MA = __builtin_exp2f( LD * (SHF(2) + SHF(3)));
    const float KB = __builtin_exp2f(-LD * (SHF(11) + SHF(12)));
    const float MB = __builtin_exp2f( LD * (SHF(10) + SHF(11)));

    const int jbase = jhalf * 256;
    #pragma unroll
    for (int jc = 0; jc < 256; jc += 64) {     // compile-time 4 iterations
        const float4 cj = sc[jbase + jc + lane];
        const float dx = ci.x - cj.x;
        const float dy = ci.y - cj.y;
        const float dz = ci.z - cj.z;
        const float sq = dx * dx + dy * dy + dz * dz;
        const float d  = __builtin_amdgcn_sqrtf(sq);
        const float dc = fminf(d, 5.3f);
        const int spj  = __float_as_int(cj.w);

        float fc = 0.5f * __builtin_amdgcn_cosf(dc * (1.0f / 10.4f)) + 0.5f;
        fc = (d > 0.0f && d <= 5.2f) ? fc : 0.0f;

        const float Lsq = L16 * sq;
        const float rb  = __builtin_amdgcn_exp2f(LD2 * dc);
        const float irb = __builtin_amdgcn_exp2f(-LD2 * dc);

        float core[16];
        {   // group A: anchor r=3
            const float argA = dc * (2.0f * L16 * SHF(3))
                             - (L16 * SHF(3) * SHF(3)) - Lsq;
            core[3] = __builtin_amdgcn_exp2f(argA);
            float t = rb * KA;
            core[4] = core[3] * t; t *= Q;
            core[5] = core[4] * t; t *= Q;
            core[6] = core[5] * t; t *= Q;
            core[7] = core[6] * t;
            float u = irb * MA;
            core[2] = core[3] * u; u *= Q;
            core[1] = core[2] * u; u *= Q;
            core[0] = core[1] * u;
        }
        {   // group B: anchor r=11
            const float argB = dc * (2.0f * L16 * SHF(11))
                             - (L16 * SHF(11) * SHF(11)) - Lsq;
            core[11] = __builtin_amdgcn_exp2f(argB);
            float t = rb * KB;
            core[12] = core[11] * t; t *= Q;
            core[13] = core[12] * t; t *= Q;
            core[14] = core[13] * t; t *= Q;
            core[15] = core[14] * t;
            float u = irb * MB;
            core[10] = core[11] * u; u *= Q;
            core[9]  = core[10] * u; u *= Q;
            core[8]  = core[9]  * u;
        }

        const float f0 = (spj == 0) ? fc : 0.0f;
        const float f1 = (spj == 1) ? fc : 0.0f;
        const float f2v = (spj == 2) ? fc : 0.0f;
        const float f3 = (spj == 3) ? fc : 0.0f;
        const f2 fc0 = {f0, f0}, fc1 = {f1, f1}, fc2 = {f2v, f2v}, fc3 = {f3, f3};

        #pragma unroll
        for (int h = 0; h < 8; ++h) {
            const f2 cp = {core[2 * h], core[2 * h + 1]};
            acc[0 * 8 + h] += cp * fc0;      // v_pk_fma_f32
            acc[1 * 8 + h] += cp * fc1;
            acc[2 * 8 + h] += cp * fc2;
            acc[3 * 8 + h] += cp * fc3;
        }
    }

    // Reduce-scatter: 5 f2 levels (m=32..2) + one float exchange (m=1).
    int cnt = 32;
    #pragma unroll
    for (int m = 32; m >= 2; m >>= 1) {
        const int half = cnt >> 1;
        const bool up = (lane & m) != 0;
        #pragma unroll
        for (int k = 0; k < half; ++k) {
            const f2 keep = up ? acc[k + half] : acc[k];
            const f2 send = up ? acc[k] : acc[k + half];
            f2 r;
            r.x = __shfl_xor(send.x, m, 64);
            r.y = __shfl_xor(send.y, m, 64);
            acc[k] = keep + r;
        }
        cnt = half;
    }
    const bool hi = (lane & 1) != 0;
    const float snd = hi ? acc[0].x : acc[0].y;
    const float rcv = __shfl_xor(snd, 1, 64);
    const float mine = (hi ? acc[0].y : acc[0].x) + rcv;  // partial (my j-half)

    // Combine the two j-halves through LDS; jhalf==1 waves store.
    if (jhalf == 0) pairbuf[aib][lane] = mine;
    __syncthreads();
    if (jhalf == 1) {
        const float v = mine + pairbuf[aib][lane];
        float* row = out + (size_t)(bb * N + i) * TARGET;
        row[lane] = v;
        float4* row4 = reinterpret_cast<float4*>(row);
        const float4 z4 = make_float4(0.0f, 0.0f, 0.0f, 0.0f);
        #pragma unroll
        for (int idx = 16 + lane; idx < 252; idx += 64) row4[idx] = z4;
    }
}

extern "C" void kernel_launch(void* const* d_in, const int* in_sizes, int n_in,
                              void* d_out, int out_size, void* d_ws, size_t ws_size,
                              hipStream_t stream) {
    const int*   species     = (const int*)d_in[0];
    const float* coordinates = (const float*)d_in[1];
    float*       out         = (float*)d_out;

    // 16 batches * 256 blocks; block = 2 atoms x 2 j-halves = 4 waves.
    dim3 grid(B * 256), block(256);
    hipLaunchKernelGGL(aev_radial_kernel, grid, block, 0, stream,
                       species, coordinates, out);
}